// Round 7
// baseline (19.758 us; speedup 1.0000x reference)
//
#include <hip/hip_runtime.h>

#define M 128
#define BT 256   // 4 waves/block; 512 blocks; all co-resident at 2 blocks/CU

typedef _Float16 half8 __attribute__((ext_vector_type(8)));
typedef __fp16 fp16x2 __attribute__((ext_vector_type(2)));
typedef float f32x4 __attribute__((ext_vector_type(4)));

// Fast-path LDS tables (per block, redundantly built):
//   sT[2^d + i]  = sp over depth-d path nodes, d=0..9
//   sV10[i]      = vals over depth-10 path nodes
//   sbuf         = 256 rows x 128B MFMA transpose buffer (c f16 -> P f32)
// Fallback (depth != 10, never taken in bench): wfb[2][128][64] column-per-thread.
struct FastMem {
  float sT[1024];
  float sV10[1024];
  int cur[1024];
  int nxt[1024];
  float4 sbuf[256 * 8];  // 32KB
};
union SMem {
  FastMem f;
  float wfb[2][M][64];  // 64KB
};

__device__ __forceinline__ float tb_gather(const float* sT, const float* sV10,
                                           int prow, int i) {
  if (prow == 0) return sT[64 + i];
  if (prow < 3) return sT[128 + 2 * i + (prow - 1)];
  if (prow < 7) return sT[256 + 4 * i + (prow - 3)];
  if (prow < 15) return sT[512 + 8 * i + (prow - 7)];
  if (prow < 31) return sV10[16 * i + (prow - 15)];
  return 0.f;
}

// A-fragment: element e of a lane's 16B frag holds k-local
// kl = (e<4) ? 4g+e : 16+4g+(e-4); i = ks*32+kl. The B operand is packed with
// the same convention, so the HW k-slot bijection cancels.
__device__ __forceinline__ half8 build_frag(const float* sT, const float* sV10,
                                            int rt, int ks, int m, int gg) {
  union { unsigned u[4]; half8 h; } r;
  const int prow = rt * 16 + m;
#pragma unroll
  for (int dw = 0; dw < 4; ++dw) {
    float v[2];
#pragma unroll
    for (int h = 0; h < 2; ++h) {
      const int e = 2 * dw + h;
      const int kl = (e < 4) ? (4 * gg + e) : (16 + 4 * gg + (e - 4));
      const int i = ks * 32 + kl;
      v[h] = tb_gather(sT, sV10, prow, i);
    }
    union { fp16x2 p; unsigned u; } pu;
    pu.p = __builtin_amdgcn_cvt_pkrtz(v[0], v[1]);
    r.u[dw] = pu.u;
  }
  return r.h;
}

#define PSTEP(S)                                                              \
  {                                                                           \
    float dot = 0.f;                                                          \
    _Pragma("unroll") for (int i = 0; i < (S); ++i)                           \
        dot = fmaf(c[i], sT[(S) + i], dot);                                   \
    const float sv = fmaf(dot, hi - lo, lo);                                  \
    tt = 1.f / (1.f + __expf((sv - xv) * 10.f));                              \
    uu = 1.f - tt;                                                            \
    const float nlo = fmaf(tt, sv, uu * lo);                                  \
    const float nhi = fmaf(tt, hi, uu * sv);                                  \
    lo = nlo; hi = nhi;                                                       \
    _Pragma("unroll") for (int i = (S)-1; i >= 0; --i) {                      \
      const float v = c[i];                                                   \
      c[2 * i + 1] = v * tt;                                                  \
      c[2 * i] = v * uu;                                                      \
    }                                                                         \
  }

#define SIGSTEP(dotv)                                   \
  {                                                     \
    const float sv = fmaf((dotv), hi - lo, lo);         \
    tt = 1.f / (1.f + __expf((sv - xv) * 10.f));        \
    uu = 1.f - tt;                                      \
    const float nlo = fmaf(tt, sv, uu * lo);            \
    const float nhi = fmaf(tt, hi, uu * sv);            \
    lo = nlo; hi = nhi;                                 \
  }

__launch_bounds__(BT)
__global__ void fractal_fused(const float* __restrict__ x,
                              const float* __restrict__ spp,
                              const float* __restrict__ vp,
                              const float* __restrict__ Lm,
                              const float* __restrict__ Rm,
                              const int* __restrict__ dpt,
                              float* __restrict__ out, int n) {
  __shared__ float ssp[M], svl[M];
  __shared__ int sli[M], sri[M];
  __shared__ SMem U;
  const int t = threadIdx.x;
  const int depth = dpt[0];

  // ---- per-block param prep (redundant across blocks, fully parallel) ----
  if (t < M) {
    ssp[t] = 1.f / (1.f + __expf(2.f - 4.f * spp[t]));
    svl[t] = vp[t & 31] * 3.f + 1.f;
  }
  {
    // one-hot column scan: threads 0..127 -> Lm rows, 128..255 -> Rm rows
    const int row = t & (M - 1);
    const float* Mt = (t < M) ? Lm : Rm;
    const float4* r4 = (const float4*)(Mt + row * M);
    int idx = 0;
#pragma unroll
    for (int j4 = 0; j4 < M / 4; ++j4) {
      const float4 v = r4[j4];
      if (v.x > 0.5f) idx = 4 * j4;
      if (v.y > 0.5f) idx = 4 * j4 + 1;
      if (v.z > 0.5f) idx = 4 * j4 + 2;
      if (v.w > 0.5f) idx = 4 * j4 + 3;
    }
    if (t < M) sli[row] = idx; else sri[row] = idx;
  }
  __syncthreads();

  if (depth == 10) {
    float* sT = U.f.sT;
    float* sV10 = U.f.sV10;
    // ---- pointer-chase table build, in LDS ----
    if (t == 0) { U.f.cur[0] = 0; sT[0] = 0.f; }
    __syncthreads();
    int S = 1;
    for (int d = 0; d <= 10; ++d) {
      for (int i = t; i < S; i += BT) {
        const int nd = U.f.cur[i];
        if (d <= 9) sT[S + i] = ssp[nd];
        else sV10[i] = svl[nd];
        if (d < 10) { U.f.nxt[2 * i] = sli[nd]; U.f.nxt[2 * i + 1] = sri[nd]; }
      }
      __syncthreads();
      if (d < 10) {
        for (int i = t; i < 2 * S; i += BT) U.f.cur[i] = U.f.nxt[i];
        __syncthreads();
      }
      S <<= 1;
    }

    // ---- per-lane A fragments from LDS tables ----
    const int lane = t & 63;
    const int col = lane & 15, g = lane >> 4;
    const half8 A00 = build_frag(sT, sV10, 0, 0, col, g);
    const half8 A01 = build_frag(sT, sV10, 0, 1, col, g);
    const half8 A10 = build_frag(sT, sV10, 1, 0, col, g);
    const half8 A11 = build_frag(sT, sV10, 1, 1, col, g);

    const int gid = blockIdx.x * BT + t;
    const float xv = (gid < n) ? x[gid] : 0.5f;

    // ---- register prefix phase (levels 1..6) ----
    float c[64];
    float lo = 0.f, hi = 1.f, tt, uu;
    c[0] = 1.f;
    PSTEP(1) PSTEP(2) PSTEP(4) PSTEP(8) PSTEP(16) PSTEP(32)

    // ---- pack c -> f16 into sbuf row t, XOR-16B swizzle ----
    char* const sb = (char*)U.f.sbuf;
    {
      char* cb = sb + t * 128;
#pragma unroll
      for (int q = 0; q < 8; ++q) {
        const int k0 = (q >> 2) * 32 + (q & 3) * 4;
        union { fp16x2 h2[4]; float4 f4; } u;
        u.h2[0] = __builtin_amdgcn_cvt_pkrtz(c[k0], c[k0 + 1]);
        u.h2[1] = __builtin_amdgcn_cvt_pkrtz(c[k0 + 2], c[k0 + 3]);
        u.h2[2] = __builtin_amdgcn_cvt_pkrtz(c[k0 + 16], c[k0 + 17]);
        u.h2[3] = __builtin_amdgcn_cvt_pkrtz(c[k0 + 18], c[k0 + 19]);
        *(float4*)(cb + ((q ^ (t & 7)) * 16)) = u.f4;
      }
    }
    __syncthreads();

    // ---- read B fragments (transposed c), wave-local rows ----
    const int wbase = (t >> 6) << 6;  // wave's first point row
    half8 bf[2][4];
#pragma unroll
    for (int ct = 0; ct < 4; ++ct) {
      const int p = wbase + 16 * ct + col;
      const char* pb = sb + p * 128;
#pragma unroll
      for (int ks = 0; ks < 2; ++ks) {
        const int q = ks * 4 + g;
        bf[ks][ct] = *(const half8*)(pb + ((q ^ (p & 7)) * 16));
      }
    }
    __syncthreads();

    // ---- P[32 x 64pts] = Bt(32x64) x C(64x64), per wave ----
    f32x4 acc[2][4];
#pragma unroll
    for (int rt = 0; rt < 2; ++rt)
#pragma unroll
      for (int ct = 0; ct < 4; ++ct) acc[rt][ct] = f32x4{0.f, 0.f, 0.f, 0.f};
#pragma unroll
    for (int ct = 0; ct < 4; ++ct) {
      acc[0][ct] = __builtin_amdgcn_mfma_f32_16x16x32_f16(A00, bf[0][ct], acc[0][ct], 0, 0, 0);
      acc[0][ct] = __builtin_amdgcn_mfma_f32_16x16x32_f16(A01, bf[1][ct], acc[0][ct], 0, 0, 0);
      acc[1][ct] = __builtin_amdgcn_mfma_f32_16x16x32_f16(A10, bf[0][ct], acc[1][ct], 0, 0, 0);
      acc[1][ct] = __builtin_amdgcn_mfma_f32_16x16x32_f16(A11, bf[1][ct], acc[1][ct], 0, 0, 0);
    }

    // ---- scatter P (D layout col=lane&15, row=(lane>>4)*4+reg; m89) ----
#pragma unroll
    for (int rt = 0; rt < 2; ++rt)
#pragma unroll
      for (int ct = 0; ct < 4; ++ct) {
        const int p = wbase + 16 * ct + col;
        const int rb = rt * 4 + g;
        *(f32x4*)(sb + p * 128 + ((rb ^ (p & 7)) * 16)) = acc[rt][ct];
      }
    __syncthreads();
    float4 P[8];
#pragma unroll
    for (int j = 0; j < 8; ++j)
      P[j] = *(const float4*)(sb + t * 128 + ((j ^ (t & 7)) * 16));

    // ---- sequential tail: rows 0 | 1..2 | 3..6 | 7..14 | 15..30 ----
    SIGSTEP(P[0].x);
    const float w20 = uu, w21 = tt;
    SIGSTEP(fmaf(w20, P[0].y, w21 * P[0].z));
    float W4[4] = {w20 * uu, w20 * tt, w21 * uu, w21 * tt};
    SIGSTEP(fmaf(W4[0], P[0].w, fmaf(W4[1], P[1].x, fmaf(W4[2], P[1].y, W4[3] * P[1].z))));
    float W8[8];
#pragma unroll
    for (int s = 3; s >= 0; --s) { W8[2 * s + 1] = W4[s] * tt; W8[2 * s] = W4[s] * uu; }
    {
      float d0 = fmaf(W8[0], P[1].w, W8[1] * P[2].x);
      float d1 = fmaf(W8[2], P[2].y, W8[3] * P[2].z);
      float d2 = fmaf(W8[4], P[2].w, W8[5] * P[3].x);
      float d3 = fmaf(W8[6], P[3].y, W8[7] * P[3].z);
      SIGSTEP((d0 + d1) + (d2 + d3));
    }
    float W16[16];
#pragma unroll
    for (int s = 7; s >= 0; --s) { W16[2 * s + 1] = W8[s] * tt; W16[2 * s] = W8[s] * uu; }
    float outv;
    {
      float d0 = fmaf(W16[0], P[3].w, W16[1] * P[4].x);
      d0 = fmaf(W16[2], P[4].y, d0); d0 = fmaf(W16[3], P[4].z, d0);
      float d1 = fmaf(W16[4], P[4].w, W16[5] * P[5].x);
      d1 = fmaf(W16[6], P[5].y, d1); d1 = fmaf(W16[7], P[5].z, d1);
      float d2 = fmaf(W16[8], P[5].w, W16[9] * P[6].x);
      d2 = fmaf(W16[10], P[6].y, d2); d2 = fmaf(W16[11], P[6].z, d2);
      float d3 = fmaf(W16[12], P[6].w, W16[13] * P[7].x);
      d3 = fmaf(W16[14], P[7].y, d3); d3 = fmaf(W16[15], P[7].z, d3);
      outv = (d0 + d1) + (d2 + d3);
    }
    if (gid < n) out[gid] = outv;
  } else {
    // ---- generic-depth fallback (never taken in bench; correctness only) ----
    // 64 active threads per block, LDS column-per-thread, grid-stride.
    for (int base = blockIdx.x * 64; base < n; base += gridDim.x * 64) {
      if (t < 64) {
        const int gid = base + t;
        if (gid < n) {
          const float xv = x[gid];
          for (int j = 0; j < M; ++j) U.wfb[0][j][t] = 0.f;
          U.wfb[0][0][t] = 1.f;
          float lo = 0.f, hi = 1.f;
          int cb = 0;
          for (int k = 0; k < depth; ++k) {
            float dot = 0.f;
            for (int j = 0; j < M; ++j) dot += U.wfb[cb][j][t] * ssp[j];
            const float sv = lo + dot * (hi - lo);
            const float tt2 = 1.f / (1.f + __expf((sv - xv) * 10.f));
            const float uu2 = 1.f - tt2;
            for (int j = 0; j < M; ++j) U.wfb[cb ^ 1][j][t] = 0.f;
            for (int j = 0; j < M; ++j) {
              const float v = U.wfb[cb][j][t];
              U.wfb[cb ^ 1][sli[j]][t] += uu2 * v;
              U.wfb[cb ^ 1][sri[j]][t] += tt2 * v;
            }
            const float nlo = uu2 * lo + tt2 * sv;
            const float nhi = uu2 * sv + tt2 * hi;
            lo = nlo; hi = nhi;
            cb ^= 1;
          }
          float acc = 0.f;
          for (int j = 0; j < M; ++j) acc += U.wfb[cb][j][t] * svl[j];
          out[gid] = acc;
        }
      }
    }
  }
}

extern "C" void kernel_launch(void* const* d_in, const int* in_sizes, int n_in,
                              void* d_out, int out_size, void* d_ws, size_t ws_size,
                              hipStream_t stream) {
  const float* x   = (const float*)d_in[0];
  const float* spp = (const float*)d_in[1];
  const float* vp  = (const float*)d_in[2];
  const float* Lm  = (const float*)d_in[3];
  const float* Rm  = (const float*)d_in[4];
  const int* dpt   = (const int*)d_in[5];
  float* out = (float*)d_out;
  const int n = in_sizes[0];

  const int blocks = (n + BT - 1) / BT;  // 512
  hipLaunchKernelGGL(fractal_fused, dim3(blocks), dim3(BT), 0, stream,
                     x, spp, vp, Lm, Rm, dpt, out, n);
}